// Round 16
// baseline (953.110 us; speedup 1.0000x reference)
//
#include <hip/hip_runtime.h>
#include <cstddef>
#include <cstdint>

static constexpr int NV = 100000;   // vertices
static constexpr int NP = 100096;   // padded to 782*128
static constexpr int ME = 25000;    // hyperedges
static constexpr int MEP = 25088;   // padded to 196*128
static constexpr int KE = 16;       // vertices per edge
static constexpr float BN_EPS = 1e-5f;

typedef unsigned int u32;
typedef __attribute__((ext_vector_type(8))) short s16x8;
typedef __attribute__((ext_vector_type(8))) unsigned short u16x8;
typedef __attribute__((ext_vector_type(4))) float f32x4;

__device__ __forceinline__ float sigm(float x) { return 1.0f / (1.0f + expf(-x)); }
__device__ __forceinline__ float bf2f(unsigned short u) {
    union { u32 i; float f; } v; v.i = ((u32)u) << 16; return v.f;
}
__device__ __forceinline__ unsigned short f2bf(float f) {
    union { float f; u32 i; } v; v.f = f;
    u32 u = v.i;
    return (unsigned short)((u + 0x7FFFu + ((u >> 16) & 1u)) >> 16);
}

#define GLD16(g, l) __builtin_amdgcn_global_load_lds(                          \
    (__attribute__((address_space(1))) const unsigned int*)(g),                \
    (__attribute__((address_space(3))) unsigned int*)(l), 16, 0, 0)

// Stage A[128x64] bf16 tile from SRC (leading dim LD) into LDS buffer b
// (linear dest, source-swizzled so swizzled ds_read_b128 is conflict-free).
#define STAGE_G(b, SRC, LD, k0)                                                \
  {                                                                            \
    unsigned short* sA_ = sm + (b) * 8192;                                     \
    _Pragma("unroll")                                                          \
    for (int i_ = 0; i_ < 4; ++i_) {                                           \
      const unsigned short* g_ = (SRC) + (size_t)(bm + 32 * w + 8 * i_ + (l >> 3)) * (LD) + (k0) + swz; \
      GLD16(g_, sA_ + 2048 * w + 512 * i_);                                    \
    }                                                                          \
  }

// ============ pipelined bf16 MFMA GEMM: C = A[NP,IC] @ W[OC,IC]^T + bias =====
// Triple-buffered A staging with COUNTED vmcnt (T4): loads for tiles t+1, t+2
// stay in flight across the barrier and the tile-t compute — never drain to 0
// in the main loop. B fragments direct from global. XCD-chunked swizzle (m204).
// fuse=0: normal store (+ optional stats). fuse=1: GRU zr. fuse=2: GRU out.
__global__ __launch_bounds__(256)
void mfma_gemm(const unsigned short* __restrict__ A, int ldA, int IC1,
               const unsigned short* __restrict__ A2, int ldA2, int IC,
               const unsigned short* __restrict__ W, const float* __restrict__ bias,
               unsigned short* __restrict__ Cb, int ldb, int cb0,
               unsigned short* __restrict__ Cb2, int ldb2, int splitN,
               float* __restrict__ s1f, float* __restrict__ s2f, int statsC,
               int fuse, const unsigned short* __restrict__ xe_p,
               const unsigned short* __restrict__ zbuf,
               unsigned short* __restrict__ rxout,
               float* __restrict__ o_outs, float* __restrict__ o_outsf,
               unsigned short* __restrict__ o_outsb)
{
    __shared__ unsigned short sm[3 * 8192];   // 48 KB: triple buffer
    const int BX = gridDim.x;
    const int total = BX * gridDim.y;
    const int flat = blockIdx.x + BX * blockIdx.y;
    const int q = total >> 3, r = total & 7;
    const int xcd = flat & 7, sub = flat >> 3;
    const int base = (xcd < r) ? xcd * (q + 1) : r * (q + 1) + (xcd - r) * q;
    const int vid = base + sub;
    const int bm = (vid / BX) * 128;
    const int bn = (vid % BX) * 64;

    const int tid = threadIdx.x;
    const int l = tid & 63, w = tid >> 6;
    const int wrow = w >> 1, wcol = w & 1;

    f32x4 acc[4][2];
    #pragma unroll
    for (int m = 0; m < 4; ++m)
        #pragma unroll
        for (int n = 0; n < 2; ++n)
            #pragma unroll
            for (int r2 = 0; r2 < 4; ++r2) acc[m][n][r2] = 0.f;

    const int swz = (((l & 7) ^ (l >> 3)) << 3);
    const int nt = IC >> 6;

    #define STAGE_T(b, t)                                                      \
      { int k0_ = (t) << 6;                                                    \
        if (k0_ < IC1) { STAGE_G(b, A, ldA, k0_) }                             \
        else           { STAGE_G(b, A2, ldA2, k0_ - IC1) } }

    STAGE_T(0, 0);
    if (nt > 1) STAGE_T(1, 1);

    for (int t = 0; t < nt; ++t) {
        if (t + 2 < nt) STAGE_T((t + 2) % 3, t + 2);
        // wait for tile t's 4 loads: keep younger tiles' loads in flight
        if (t + 2 < nt)      asm volatile("s_waitcnt vmcnt(8)" ::: "memory");
        else if (t + 1 < nt) asm volatile("s_waitcnt vmcnt(4)" ::: "memory");
        else                 asm volatile("s_waitcnt vmcnt(0)" ::: "memory");
        __builtin_amdgcn_s_barrier();
        const unsigned short* sA = sm + (t % 3) * 8192;
        #pragma unroll
        for (int ks = 0; ks < 2; ++ks) {
            const int koff = ks * 32 + ((l >> 4) << 3);
            s16x8 afr[4], bfr[2];
            #pragma unroll
            for (int m = 0; m < 4; ++m) {
                int row = wrow * 64 + m * 16 + (l & 15);
                afr[m] = *(const s16x8*)&sA[row * 64 + (koff ^ ((l & 7) << 3))];
            }
            #pragma unroll
            for (int n = 0; n < 2; ++n) {
                int col = bn + wcol * 32 + n * 16 + (l & 15);
                bfr[n] = *(const s16x8*)&W[(size_t)col * IC + (t << 6) + koff];
            }
            #pragma unroll
            for (int m = 0; m < 4; ++m)
                #pragma unroll
                for (int n = 0; n < 2; ++n)
                    acc[m][n] = __builtin_amdgcn_mfma_f32_16x16x32_bf16(
                        afr[m], bfr[n], acc[m][n], 0, 0, 0);
        }
        __builtin_amdgcn_s_barrier();   // all waves done reading buf t%3
    }
    #undef STAGE_T

    if (fuse == 1) {
        #pragma unroll
        for (int n = 0; n < 2; ++n) {
            const int col = bn + wcol * 32 + n * 16 + (l & 15);
            const float bs = bias[col];
            #pragma unroll
            for (int m = 0; m < 4; ++m) {
                const int row0 = bm + wrow * 64 + m * 16 + ((l >> 4) << 2);
                #pragma unroll
                for (int r2 = 0; r2 < 4; ++r2) {
                    const int row = row0 + r2;
                    float v = acc[m][n][r2] + bs;
                    if (col < 128) {
                        Cb[(size_t)row * 128 + col] = f2bf(v);
                    } else {
                        float xe = bf2f(xe_p[(size_t)row * 128 + col - 128]);
                        rxout[(size_t)row * 128 + col - 128] = f2bf(sigm(v) * xe);
                    }
                }
            }
        }
        return;
    }
    if (fuse == 2) {
        #pragma unroll
        for (int n = 0; n < 2; ++n) {
            const int col = bn + wcol * 32 + n * 16 + (l & 15);
            const float bs = bias[col];
            #pragma unroll
            for (int m = 0; m < 4; ++m) {
                const int row0 = bm + wrow * 64 + m * 16 + ((l >> 4) << 2);
                #pragma unroll
                for (int r2 = 0; r2 < 4; ++r2) {
                    const int row = row0 + r2;
                    if (row < NV) {
                        float z = sigm(bf2f(zbuf[(size_t)row * 128 + col]));
                        float xe = bf2f(xe_p[(size_t)row * 128 + col]);
                        float val = z * tanhf(acc[m][n][r2] + bs) + (1.f - z) * xe;
                        o_outs[(size_t)row * 128 + col] = val;
                        if (o_outsf) o_outsf[(size_t)row * 128 + col] = val;
                        o_outsb[(size_t)row * 128 + col] = f2bf(val);
                    }
                }
            }
        }
        return;
    }

    unsigned short* dst = Cb;
    int ld = ldb, co = cb0;
    if (Cb2 && bn >= splitN) { dst = Cb2; ld = ldb2; co = -splitN; }

    #pragma unroll
    for (int n = 0; n < 2; ++n) {
        const int col = bn + wcol * 32 + n * 16 + (l & 15);
        const float bs = bias[col];
        float ssum = 0.f, sq = 0.f;
        #pragma unroll
        for (int m = 0; m < 4; ++m) {
            const int row0 = bm + wrow * 64 + m * 16 + ((l >> 4) << 2);
            #pragma unroll
            for (int r2 = 0; r2 < 4; ++r2) {
                float v = acc[m][n][r2] + bs;
                int row = row0 + r2;
                if (dst) dst[(size_t)row * ld + co + col] = f2bf(v);
                if (s1f && col < statsC && row < NV) { ssum += v; sq += v * v; }
            }
        }
        if (s1f && col < statsC) {
            ssum += __shfl_xor(ssum, 16); ssum += __shfl_xor(ssum, 32);
            sq   += __shfl_xor(sq, 16);   sq   += __shfl_xor(sq, 32);
            if ((l >> 4) == 0) {
                atomicAdd(&s1f[col], ssum);
                atomicAdd(&s2f[col], sq);
            }
        }
    }
}

// ===== edge-domain GEMM (IC=128, B direct from global, XCD swizzle).
// Both K-tiles staged up-front; counted vmcnt(4) before the first compute.
__global__ __launch_bounds__(256)
void mfma_gemm_ef2(const unsigned short* __restrict__ A,   // ge [MEP,128]
                   const unsigned short* __restrict__ W,   // [OC,128]
                   const float* __restrict__ we,
                   const float* __restrict__ P, const float* __restrict__ Q,
                   unsigned short* __restrict__ ef0, unsigned short* __restrict__ ef1)
{
    const int ldA = 128;
    __shared__ unsigned short sm[2 * 8192];
    const int BX = gridDim.x;
    const int total = BX * gridDim.y;
    const int flat = blockIdx.x + BX * blockIdx.y;
    const int q = total >> 3, rr = total & 7;
    const int xcd = flat & 7, sub = flat >> 3;
    const int base = (xcd < rr) ? xcd * (q + 1) : rr * (q + 1) + (xcd - rr) * q;
    const int vid = base + sub;
    const int bm = (vid / BX) * 128;
    const int bn = (vid % BX) * 64;

    const int tid = threadIdx.x;
    const int l = tid & 63, w = tid >> 6;
    const int wrow = w >> 1, wcol = w & 1;

    f32x4 acc[4][2];
    #pragma unroll
    for (int m = 0; m < 4; ++m)
        #pragma unroll
        for (int n = 0; n < 2; ++n)
            #pragma unroll
            for (int r = 0; r < 4; ++r) acc[m][n][r] = 0.f;

    const int swz = (((l & 7) ^ (l >> 3)) << 3);

    STAGE_G(0, A, ldA, 0);
    STAGE_G(1, A, ldA, 64);

    #pragma unroll
    for (int t = 0; t < 2; ++t) {
        if (t == 0) asm volatile("s_waitcnt vmcnt(4)" ::: "memory");
        else        asm volatile("s_waitcnt vmcnt(0)" ::: "memory");
        __builtin_amdgcn_s_barrier();
        const unsigned short* sA = sm + t * 8192;
        #pragma unroll
        for (int ks = 0; ks < 2; ++ks) {
            const int koff = ks * 32 + ((l >> 4) << 3);
            s16x8 afr[4], bfr[2];
            #pragma unroll
            for (int m = 0; m < 4; ++m) {
                int row = wrow * 64 + m * 16 + (l & 15);
                afr[m] = *(const s16x8*)&sA[row * 64 + (koff ^ ((l & 7) << 3))];
            }
            #pragma unroll
            for (int n = 0; n < 2; ++n) {
                int col = bn + wcol * 32 + n * 16 + (l & 15);
                bfr[n] = *(const s16x8*)&W[(size_t)col * 128 + (t << 6) + koff];
            }
            #pragma unroll
            for (int m = 0; m < 4; ++m)
                #pragma unroll
                for (int n = 0; n < 2; ++n)
                    acc[m][n] = __builtin_amdgcn_mfma_f32_16x16x32_bf16(
                        afr[m], bfr[n], acc[m][n], 0, 0, 0);
        }
    }

    unsigned short* dst = (bn < 512) ? ef0 : ef1;
    const int co = (bn < 512) ? 0 : -512;

    #pragma unroll
    for (int n = 0; n < 2; ++n) {
        const int colg = bn + wcol * 32 + n * 16 + (l & 15);
        const float pc = P[colg], qc = Q[colg];
        #pragma unroll
        for (int m = 0; m < 4; ++m) {
            const int row0 = bm + wrow * 64 + m * 16 + ((l >> 4) << 2);
            #pragma unroll
            for (int r = 0; r < 4; ++r) {
                int row = row0 + r;
                if (row < ME) {
                    float wv = we[row];
                    dst[(size_t)row * 512 + co + colg] = f2bf(wv * (pc * acc[m][n][r] + qc));
                }
            }
        }
    }
}

// ===== covariance: cov[i][j] = sum_{v<NV} A[v,i]*A[v,j]  (A bf16 [NP,128]) ====
__global__ __launch_bounds__(256)
void cov_kernel(const unsigned short* __restrict__ A, float* __restrict__ cov)
{
    __shared__ unsigned short T[128 * 64];
    const int tid = threadIdx.x;
    const int l = tid & 63, w = tid >> 6;

    f32x4 acc[2][8];
    #pragma unroll
    for (int m = 0; m < 2; ++m)
        #pragma unroll
        for (int n = 0; n < 8; ++n)
            #pragma unroll
            for (int r = 0; r < 4; ++r) acc[m][n][r] = 0.f;

    const int r0 = blockIdx.x * 1024;
    for (int ch = 0; ch < 16; ++ch) {
        const int rbase = r0 + ch * 64;
        __syncthreads();
        #pragma unroll
        for (int q = 0; q < 4; ++q) {
            int idx = tid + q * 256;
            int r = idx & 63, cg = idx >> 6;
            int row = rbase + r;
            u16x8 u = {0, 0, 0, 0, 0, 0, 0, 0};
            if (row < NV) u = *(const u16x8*)&A[(size_t)row * 128 + cg * 8];
            #pragma unroll
            for (int j = 0; j < 8; ++j) {
                int c = cg * 8 + j;
                T[c * 64 + (r ^ ((c & 7) << 3))] = u[j];
            }
        }
        __syncthreads();
        #pragma unroll
        for (int ks = 0; ks < 2; ++ks) {
            const int koff = ks * 32 + ((l >> 4) << 3);
            s16x8 fi[2], fj[8];
            #pragma unroll
            for (int m = 0; m < 2; ++m) {
                int c = (w * 2 + m) * 16 + (l & 15);
                fi[m] = *(const s16x8*)&T[c * 64 + (koff ^ ((c & 7) << 3))];
            }
            #pragma unroll
            for (int n = 0; n < 8; ++n) {
                int c = n * 16 + (l & 15);
                fj[n] = *(const s16x8*)&T[c * 64 + (koff ^ ((c & 7) << 3))];
            }
            #pragma unroll
            for (int m = 0; m < 2; ++m)
                #pragma unroll
                for (int n = 0; n < 8; ++n)
                    acc[m][n] = __builtin_amdgcn_mfma_f32_16x16x32_bf16(
                        fi[m], fj[n], acc[m][n], 0, 0, 0);
        }
    }
    #pragma unroll
    for (int m = 0; m < 2; ++m) {
        #pragma unroll
        for (int n = 0; n < 8; ++n) {
            #pragma unroll
            for (int r = 0; r < 4; ++r) {
                int row = (w * 2 + m) * 16 + ((l >> 4) << 2) + r;
                int col = n * 16 + (l & 15);
                atomicAdd(&cov[row * 128 + col], acc[m][n][r]);
            }
        }
    }
}

// ===== BN stats from covariance ==============================================
__global__ __launch_bounds__(128)
void quadform_kernel(const float* __restrict__ cov, const float* __restrict__ colsum,
                     const unsigned short* __restrict__ Wt, const float* __restrict__ bias,
                     float* __restrict__ s1, float* __restrict__ s2)
{
    const int c = blockIdx.x, i = threadIdx.x;
    __shared__ float wv[128];
    __shared__ float red[128][2];
    float wi = bf2f(Wt[c * 128 + i]);
    wv[i] = wi;
    __syncthreads();
    const float* crow = cov + i * 128;
    float dot = 0.f;
    #pragma unroll 8
    for (int j = 0; j < 128; ++j) dot += crow[j] * wv[j];
    red[i][0] = wi * dot;
    red[i][1] = wi * colsum[i];
    __syncthreads();
    for (int s = 64; s > 0; s >>= 1) {
        if (i < s) { red[i][0] += red[i + s][0]; red[i][1] += red[i + s][1]; }
        __syncthreads();
    }
    if (i == 0) {
        float b = bias[c];
        float ws = red[0][1];
        s1[c] = ws + (float)NV * b;
        s2[c] = red[0][0] + 2.f * b * ws + (float)NV * b * b;
    }
}

// ================= weight prep ================================================
__global__ void prep_weights(const float* e1, const float* e2, const float* fcw,
                             const float* d1, const float* dc1, const float* dc2,
                             const float* ds2,
                             const float* f1u, const float* f2u,
                             const float* f1r, const float* f2r,
                             const float* f1, const float* f2,
                             const float* f1ub, const float* f2ub,
                             const float* f1rb, const float* f2rb,
                             const float* f1b, const float* f2b,
                             const float* ds1b, const float* dc1b,
                             const float* e2b, const float* fcb,
                             unsigned short* WB, float* bzr, float* bo,
                             float* bdd, float* bef)
{
    int i = blockIdx.x * 256 + threadIdx.x;
    if (i < 65536)           WB[i] = f2bf(e1[i]);
    else if (i < 131072)     WB[i] = f2bf(e2[i - 65536]);
    else if (i < 196608)     WB[i] = f2bf(fcw[i - 131072]);
    else if (i < 262144)     WB[i] = f2bf(d1[i - 196608]);
    else if (i < 327680)     WB[i] = f2bf(dc1[i - 262144]);
    else if (i < 393216)     WB[i] = f2bf(dc2[i - 327680]);
    else if (i < 394240)     WB[i] = f2bf(ds2[i - 393216]);
    else if (i < 459776) {
        int j = i - 394240, row = j >> 8, c = j & 255;
        float v;
        if (row < 128) v = (c < 128) ? f1u[row * 128 + c] : f2u[row * 128 + c - 128];
        else { int rr = row - 128; v = (c < 128) ? f1r[rr * 128 + c] : f2r[rr * 128 + c - 128]; }
        WB[i] = f2bf(v);
    } else if (i < 492544) {
        int j = i - 459776, row = j >> 8, c = j & 255;
        float v = (c < 128) ? f1[row * 128 + c] : f2[row * 128 + c - 128];
        WB[i] = f2bf(v);
    } else if (i < 492800) {
        int o = i - 492544;
        bzr[o] = (o < 128) ? (f1ub[o] + f2ub[o]) : (f1rb[o - 128] + f2rb[o - 128]);
    } else if (i < 492928) {
        int o = i - 492800;
        bo[o] = f1b[o] + f2b[o];
    } else if (i < 493952) {
        int o = i - 492928;
        bdd[o] = (o < 512) ? ds1b[o] : dc1b[o - 512];
    } else if (i < 494208) {
        int o = i - 493952;
        bef[o] = (o < 128) ? e2b[o] : fcb[o - 128];
    }
}

__global__ void cvt_f32_bf16(const float* __restrict__ in, unsigned short* __restrict__ out, int n)
{
    int i = (blockIdx.x * 256 + threadIdx.x) * 4;
    if (i < n) {
        float4 v = *reinterpret_cast<const float4*>(&in[i]);
        out[i] = f2bf(v.x); out[i + 1] = f2bf(v.y);
        out[i + 2] = f2bf(v.z); out[i + 3] = f2bf(v.w);
    }
}

// ================= BN finalize (scale/shift form, output-side convs) ==========
__global__ void bn_finalize_kernel(const float* __restrict__ s1, const float* __restrict__ s2,
                                   const float* __restrict__ g, const float* __restrict__ bt,
                                   float* __restrict__ scale, float* __restrict__ shift,
                                   int C, float invN)
{
    int c = threadIdx.x;
    if (c < C) {
        float m = s1[c] * invN;
        float v = fmaxf(s2[c] * invN - m * m, 0.f);
        float sc = g[c] * rsqrtf(v + BN_EPS);
        scale[c] = sc;
        shift[c] = bt[c] - m * sc;
    }
}

// ===== BN finalize (P/Q form, edge-domain convs): P=scale/K, Q=scale*b+shift ==
__global__ void bn_finalize_pq(const float* __restrict__ s1, const float* __restrict__ s2,
                               const float* __restrict__ g, const float* __restrict__ bt,
                               const float* __restrict__ bias,
                               float* __restrict__ P, float* __restrict__ Q,
                               int C, int off, float invN)
{
    int c = threadIdx.x;
    if (c < C) {
        int cc = off + c;
        float m = s1[cc] * invN;
        float v = fmaxf(s2[cc] * invN - m * m, 0.f);
        float sc = g[c] * rsqrtf(v + BN_EPS);
        float sh = bt[c] - m * sc;
        P[cc] = sc * (1.0f / KE);
        Q[cc] = sc * bias[c] + sh;
    }
}

// ========== edge gather of raw input: ge[e,c] = sum_k x[v_k,c] ================
__global__ __launch_bounds__(256)
void edge_gather_sum(const unsigned short* __restrict__ x, const int* __restrict__ vidx,
                     unsigned short* __restrict__ ge)
{
    const int e = blockIdx.x * 16 + (threadIdx.x >> 4);
    const int cp = (threadIdx.x & 15) << 3;
    if (e >= ME) return;
    float s[8] = {};
    const int* vi = vidx + e * KE;
    #pragma unroll
    for (int k = 0; k < KE; ++k) {
        int v = vi[k];
        u16x8 u = *(const u16x8*)&x[(size_t)v * 128 + cp];
        #pragma unroll
        for (int j = 0; j < 8; ++j) s[j] += bf2f(u[j]);
    }
    u16x8 o;
    #pragma unroll
    for (int j = 0; j < 8; ++j) o[j] = f2bf(s[j]);
    *(u16x8*)&ge[(size_t)e * 128 + cp] = o;
}

// ========== edge gather (bf16, fused BN), output-side convs (C=128) ===========
__global__ __launch_bounds__(256)
void edge_gather_bf(const unsigned short* __restrict__ pre, const int* __restrict__ vidx,
                    const float* __restrict__ we, const float* __restrict__ scl,
                    const float* __restrict__ shf, unsigned short* __restrict__ ef, int C)
{
    const int tpe = C >> 3;
    const int epb = 256 / tpe;
    const int e = blockIdx.x * epb + threadIdx.x / tpe;
    const int cp = (threadIdx.x % tpe) << 3;
    if (e >= ME) return;
    float s[8] = {};
    const int* vi = vidx + e * KE;
    #pragma unroll
    for (int k = 0; k < KE; ++k) {
        int v = vi[k];
        u16x8 u = *(const u16x8*)&pre[(size_t)v * C + cp];
        #pragma unroll
        for (int j = 0; j < 8; ++j) s[j] += bf2f(u[j]);
    }
    float wv = we[e] * (1.0f / KE);
    u16x8 o;
    #pragma unroll
    for (int j = 0; j < 8; ++j)
        o[j] = f2bf(wv * (scl[cp + j] * s[j] + (float)KE * shf[cp + j]));
    *(u16x8*)&ef[(size_t)e * C + cp] = o;
}

// f32 variant for C == 2 (dis2 path)
__global__ void edge_gather2_kernel(const float* __restrict__ X, const int* __restrict__ vidx,
                                    const float* __restrict__ we, const float* __restrict__ scale,
                                    const float* __restrict__ shift, float* __restrict__ ef)
{
    int e = blockIdx.x * blockDim.x + threadIdx.x;
    if (e >= ME) return;
    float s0 = 0.f, s1v = 0.f;
    #pragma unroll
    for (int k = 0; k < KE; ++k) {
        int v = vidx[e * KE + k];
        s0 += X[2 * v];
        s1v += X[2 * v + 1];
    }
    float w = we[e] * (1.0f / KE);
    ef[2 * e]     = w * (scale[0] * s0 + (float)KE * shift[0]);
    ef[2 * e + 1] = w * (scale[1] * s1v + (float)KE * shift[1]);
}

// ================= CSR build ===================================================
__global__ void deg_kernel(const int* __restrict__ vidx, int* __restrict__ deg)
{
    int i = blockIdx.x * blockDim.x + threadIdx.x;
    if (i < ME * KE) atomicAdd(&deg[vidx[i]], 1);
}

__global__ void scan_block_kernel(const int* __restrict__ deg, int* __restrict__ rowptr,
                                  int* __restrict__ blocksums, int n)
{
    __shared__ int tmp[256];
    int i = blockIdx.x * 256 + threadIdx.x;
    int v = (i < n) ? deg[i] : 0;
    tmp[threadIdx.x] = v;
    __syncthreads();
    for (int off = 1; off < 256; off <<= 1) {
        int t = (threadIdx.x >= off) ? tmp[threadIdx.x - off] : 0;
        __syncthreads();
        tmp[threadIdx.x] += t;
        __syncthreads();
    }
    if (i < n) rowptr[i] = tmp[threadIdx.x] - v;
    if (threadIdx.x == 255) blocksums[blockIdx.x] = tmp[255];
}

__global__ void scan_sums_par(int* __restrict__ bs, int nb)
{
    __shared__ int tmp[512];
    int t = threadIdx.x;
    int v = (t < nb) ? bs[t] : 0;
    tmp[t] = v;
    __syncthreads();
    for (int off = 1; off < 512; off <<= 1) {
        int u = (t >= off) ? tmp[t - off] : 0;
        __syncthreads();
        tmp[t] += u;
        __syncthreads();
    }
    if (t < nb) bs[t] = tmp[t] - v;
}

__global__ void scan_add_kernel(int* __restrict__ rowptr, const int* __restrict__ blocksums, int n)
{
    int i = blockIdx.x * 256 + threadIdx.x;
    if (i < n) rowptr[i] += blocksums[blockIdx.x];
    if (i == 0) rowptr[n] = ME * KE;
}

__global__ void csr_fill_kernel(const int* __restrict__ vidx, int* __restrict__ cursor,
                                int* __restrict__ csr)
{
    int i = blockIdx.x * blockDim.x + threadIdx.x;
    if (i < ME * KE) {
        int v = vidx[i];
        int pos = atomicAdd(&cursor[v], 1);
        csr[pos] = i >> 4;
    }
}

// ===== e->v via CSR gather (bf16 ef rows, stride ldE, col offset cb0E) ========
__global__ __launch_bounds__(256)
void csr_gather_bf(const unsigned short* __restrict__ ef, int ldE, int cb0E,
                   const int* __restrict__ rowptr, const int* __restrict__ csr,
                   float* __restrict__ outf, int ldf,
                   unsigned short* __restrict__ outb, int ldb, int cb0,
                   unsigned short* __restrict__ outb2, int ldb2,
                   int C, int relu)
{
    const int lpv = C >> 3;
    const int vpb = 256 / lpv;
    const int v = blockIdx.x * vpb + threadIdx.x / lpv;
    const int lg = threadIdx.x % lpv;
    if (v >= NV) return;
    const int s = rowptr[v], e = rowptr[v + 1];
    float a[8] = {};
    int i = s;
    for (; i + 2 <= e; i += 2) {
        int e0 = csr[i], e1 = csr[i + 1];
        u16x8 u0 = *(const u16x8*)&ef[(size_t)e0 * ldE + cb0E + lg * 8];
        u16x8 u1 = *(const u16x8*)&ef[(size_t)e1 * ldE + cb0E + lg * 8];
        #pragma unroll
        for (int j = 0; j < 8; ++j) a[j] += bf2f(u0[j]) + bf2f(u1[j]);
    }
    if (i < e) {
        int e0 = csr[i];
        u16x8 u0 = *(const u16x8*)&ef[(size_t)e0 * ldE + cb0E + lg * 8];
        #pragma unroll
        for (int j = 0; j < 8; ++j) a[j] += bf2f(u0[j]);
    }
    float inv = 1.0f / (float)max(e - s, 1);
    #pragma unroll
    for (int j = 0; j < 8; ++j) {
        float x = a[j] * inv;
        if (relu) x = fmaxf(x, 0.f);
        a[j] = x;
    }
    if (outf) {
        float* p = outf + (size_t)v * ldf + lg * 8;
        #pragma unroll
        for (int j = 0; j < 8; ++j) p[j] = a[j];
    }
    if (outb) {
        u16x8 o;
        #pragma unroll
        for (int j = 0; j < 8; ++j) o[j] = f2bf(a[j]);
        *(u16x8*)&outb[(size_t)v * ldb + cb0 + lg * 8] = o;
    }
    if (outb2) {
        u16x8 o;
        #pragma unroll
        for (int j = 0; j < 8; ++j) o[j] = f2bf(a[j]);
        *(u16x8*)&outb2[(size_t)v * ldb2 + lg * 8] = o;
    }
}

// ===== dis-half gather: aggregate hdis row (relu) and dot with wdis2 ->
// pre22 directly (in-wave 64-lane reduce, no atomics).
__global__ __launch_bounds__(256)
void csr_gather_dis(const unsigned short* __restrict__ ef,   // [MEP,512] dis half
                    const int* __restrict__ rowptr, const int* __restrict__ csr,
                    const unsigned short* __restrict__ wdis2, const float* __restrict__ dis2b,
                    float* __restrict__ pre22)
{
    const int w = threadIdx.x >> 6, l = threadIdx.x & 63;
    const int v = blockIdx.x * 4 + w;
    if (v >= NV) return;
    const int s = rowptr[v], e = rowptr[v + 1];
    float a[8] = {};
    int i = s;
    for (; i + 2 <= e; i += 2) {
        int e0 = csr[i], e1 = csr[i + 1];
        u16x8 u0 = *(const u16x8*)&ef[(size_t)e0 * 512 + l * 8];
        u16x8 u1 = *(const u16x8*)&ef[(size_t)e1 * 512 + l * 8];
        #pragma unroll
        for (int j = 0; j < 8; ++j) a[j] += bf2f(u0[j]) + bf2f(u1[j]);
    }
    if (i < e) {
        int e0 = csr[i];
        u16x8 u0 = *(const u16x8*)&ef[(size_t)e0 * 512 + l * 8];
        #pragma unroll
        for (int j = 0; j < 8; ++j) a[j] += bf2f(u0[j]);
    }
    float inv = 1.0f / (float)max(e - s, 1);
    u16x8 w0 = *(const u16x8*)&wdis2[l * 8];
    u16x8 w1 = *(const u16x8*)&wdis2[512 + l * 8];
    float d0 = 0.f, d1 = 0.f;
    #pragma unroll
    for (int j = 0; j < 8; ++j) {
        float h = fmaxf(a[j] * inv, 0.f);
        d0 += h * bf2f(w0[j]);
        d1 += h * bf2f(w1[j]);
    }
    for (int o = 32; o > 0; o >>= 1) {
        d0 += __shfl_down(d0, o);
        d1 += __shfl_down(d1, o);
    }
    if (l == 0) {
        pre22[2 * v]     = d0 + dis2b[0];
        pre22[2 * v + 1] = d1 + dis2b[1];
    }
}

__global__ void csr_gather2_kernel(const float* __restrict__ ef, const int* __restrict__ rowptr,
                                   const int* __restrict__ csr, float* __restrict__ outp)
{
    int v = blockIdx.x * blockDim.x + threadIdx.x;
    if (v >= NV) return;
    int s = rowptr[v], e = rowptr[v + 1];
    float a0 = 0.f, a1 = 0.f;
    for (int i = s; i < e; ++i) {
        int ed = csr[i];
        a0 += ef[2 * ed];
        a1 += ef[2 * ed + 1];
    }
    float inv = 1.0f / (float)max(e - s, 1);
    outp[2 * v]     = a0 * inv;
    outp[2 * v + 1] = a1 * inv;
}

// ========== column stats over bf16 [NP,128] ws buffer =========================
__global__ __launch_bounds__(256)
void colstats_bf(const unsigned short* __restrict__ Xb,
                 float* __restrict__ s1, float* __restrict__ s2)
{
    const int t = threadIdx.x;
    const int cg = t & 15;
    const int rs = t >> 4;
    float s[8] = {}, q[8] = {};
    for (int r = blockIdx.x * 16 + rs; r < NV; r += 256 * 16) {
        u16x8 u = *(const u16x8*)&Xb[(size_t)r * 128 + cg * 8];
        #pragma unroll
        for (int j = 0; j < 8; ++j) {
            float v = bf2f(u[j]);
            s[j] += v; q[j] += v * v;
        }
    }
    __shared__ float ls[16][16][8];
    __shared__ float lq[16][16][8];
    #pragma unroll
    for (int j = 0; j < 8; ++j) { ls[rs][cg][j] = s[j]; lq[rs][cg][j] = q[j]; }
    __syncthreads();
    int c = t & 127;
    float a = 0.f;
    if (t < 128) {
        #pragma unroll
        for (int i = 0; i < 16; ++i) a += ls[i][c >> 3][c & 7];
        atomicAdd(&s1[c], a);
    } else {
        #pragma unroll
        for (int i = 0; i < 16; ++i) a += lq[i][c >> 3][c & 7];
        atomicAdd(&s2[c], a);
    }
}

__global__ void att_finalize_kernel(const float* __restrict__ s1, const float* __restrict__ s2,
                                    float* __restrict__ mu, float* __restrict__ qd, int C)
{
    int c = threadIdx.x;
    if (c < C) {
        float m = s1[c] / (float)NV;
        float vv = fmaxf((s2[c] - (float)NV * m * m) / (float)(NV - 1), 0.f);
        mu[c] = m;
        qd[c] = 1.0f / (4.0f * (vv + 0.001f));
    }
}

// ========== proto over outsb (bf16 ws), grid-stride + LDS reduce ==============
__global__ __launch_bounds__(256)
void proto_bf(const unsigned short* __restrict__ Xb, const float* __restrict__ mu,
              const float* __restrict__ qd, float* __restrict__ proto)
{
    const int t = threadIdx.x;
    const int cg = t & 15;
    const int rs = t >> 4;
    float m[8], q[8], a[8] = {};
    #pragma unroll
    for (int j = 0; j < 8; ++j) { m[j] = mu[cg * 8 + j]; q[j] = qd[cg * 8 + j]; }
    for (int r = blockIdx.x * 16 + rs; r < NV; r += 256 * 16) {
        u16x8 u = *(const u16x8*)&Xb[(size_t)r * 128 + cg * 8];
        #pragma unroll
        for (int j = 0; j < 8; ++j) {
            float x = bf2f(u[j]);
            float d = x - m[j];
            a[j] += x * sigm(d * d * q[j] + 0.5f);
        }
    }
    __shared__ float ls[16][16][8];
    #pragma unroll
    for (int j = 0; j < 8; ++j) ls[rs][cg][j] = a[j];
    __syncthreads();
    if (t < 128) {
        float acc = 0.f;
        #pragma unroll
        for (int i = 0; i < 16; ++i) acc += ls[i][t >> 3][t & 7];
        atomicAdd(&proto[t], acc);
    }
}

// ================= stats for C==2 ==============================================
__global__ void colstats2_kernel(const float* __restrict__ X, int N,
                                 float* __restrict__ s1, float* __restrict__ s2)
{
    __shared__ float red[256][4];
    int t = threadIdx.x;
    float a0 = 0, a1 = 0, b0 = 0, b1 = 0;
    for (int r = blockIdx.x * 256 + t; r < N; r += 256 * gridDim.x) {
        float x0 = X[2 * r], x1 = X[2 * r + 1];
        a0 += x0; b0 += x0 * x0;
        a1 += x1; b1 += x1 * x1;
    }
    red[t][0] = a0; red[t][1] = a1; red[t][2] = b0; red[t][3] = b1;
    __syncthreads();
    for (int s = 128; s > 0; s >>= 1) {
        if (t < s)
            for (int j = 0; j < 4; ++j) red[t][j] += red[t + s][j];
        __syncthreads();
    }
    if (t == 0) {
        atomicAdd(&s1[0], red[0][0]);
        atomicAdd(&s1[1], red[0][1]);
        atomicAdd(&s2[0], red[0][2]);
        atomicAdd(&s2[1], red[0][3]);
    }
}

// ==============================================================================
extern "C" void kernel_launch(void* const* d_in, const int* in_sizes, int n_in,
                              void* d_out, int out_size, void* d_ws, size_t ws_size,
                              hipStream_t stream)
{
    const float* X      = (const float*)d_in[0];
    const int*   vidx   = (const int*)  d_in[1];
    const float* we     = (const float*)d_in[2];
    const float* enc1_W = (const float*)d_in[3];  const float* enc1_b = (const float*)d_in[4];
    const float* enc2_W = (const float*)d_in[5];  const float* enc2_b = (const float*)d_in[6];
    const float* fc_W   = (const float*)d_in[7];  const float* fc_b   = (const float*)d_in[8];
    const float* f1u_W  = (const float*)d_in[9];  const float* f1u_b  = (const float*)d_in[10];
    const float* f2u_W  = (const float*)d_in[11]; const float* f2u_b  = (const float*)d_in[12];
    const float* f1r_W  = (const float*)d_in[13]; const float* f1r_b  = (const float*)d_in[14];
    const float* f2r_W  = (const float*)d_in[15]; const float* f2r_b  = (const float*)d_in[16];
    const float* f1_W   = (const float*)d_in[17]; const float* f1_b   = (const float*)d_in[18];
    const float* f2_W   = (const float*)d_in[19]; const float* f2_b   = (const float*)d_in[20];
    const float* dis1_W = (const float*)d_in[21]; const float* dis1_b = (const float*)d_in[22];
    const float* dis2_W = (const float*)d_in[23]; const float* dis2_b = (const float*)d_in[24];
    const float* dec1_W = (const float*)d_in[25]; const float* dec1_b = (const float*)d_in[26];
    const float* dec2_W = (const float*)d_in[27]; const float* dec2_b = (const float*)d_in[28];
    const float* enc1_g = (const float*)d_in[29]; const float* enc1_bt = (const float*)d_in[30];
    const float* enc2_g = (const float*)d_in[31]; const float* enc2_bt = (const float*)d_in[32];
    const float* dis1_g = (const float*)d_in[33]; const float* dis1_bt = (const float*)d_in[34];
    const float* dis2_g = (const float*)d_in[35]; const float* dis2_bt = (const float*)d_in[36];
    const float* dec1_g = (const float*)d_in[37]; const float* dec1_bt = (const float*)d_in[38];
    const float* dec2_g = (const float*)d_in[39]; const float* dec2_bt = (const float*)d_in[40];

    float* out   = (float*)d_out;
    float* outs  = out;                   // [N,128]
    float* x_de  = out + 12800000;        // [N,128]
    float* proto = out + 25600000;        // [128]
    float* xdis  = out + 25600128;        // [N,2]

    // ---------------- workspace layout ----------------
    char* base = (char*)d_ws;
    unsigned short* bufA = (unsigned short*)base;                 // [NP,512] bf16
    char* p = base + (size_t)NP * 512 * 2;
    unsigned short* bufE = (unsigned short*)p; p += (size_t)MEP * 1024 * 2;   // 2x [MEP,512]
    unsigned short* Greg = (unsigned short*)p;                    // [NP,256] bf16
    unsigned short* Xbf  = Greg;                                  // [NP,128]
    p += (size_t)NP * 256 * 2;
    unsigned short* x1bf = (unsigned short*)p; p += (size_t)NP * 512 * 2;
    unsigned short* WB = (unsigned short*)p; p += 492544 * 2 + 1024;
    float* bzr = (float*)p; p += 256 * 4;
    float* bo  = (float*)p; p += 128 * 4;
    float* bdd = (float*)p; p += 1024 * 4;
    float* bef = (float*)p; p += 256 * 4;
    float* s1  = (float*)p; p += 1024 * 4;
    float* s2  = (float*)p; p += 1024 * 4;
    float* scl = (float*)p; p += 1024 * 4;   // also P
    float* shf = (float*)p; p += 1024 * 4;   // also Q
    float* sX1 = (float*)p; p += 128 * 4;
    float* sX2 = (float*)p; p += 128 * 4;
    float* sA1 = (float*)p; p += 128 * 4;
    float* sA2 = (float*)p; p += 128 * 4;
    float* covX = (float*)p; p += 16384 * 4;
    float* covA = (float*)p; p += 16384 * 4;
    int* deg    = (int*)p; p += (size_t)NV * 4;
    int* rowptr = (int*)p; p += (size_t)(NV + 1) * 4;
    int* cursor = (int*)p; p += (size_t)NV * 4;
    int* bsums  = (int*)p; p += 512 * 4;
    int* csr    = (int*)p; p += (size_t)ME * KE * 4;
    unsigned short* ge = (unsigned short*)p;                      // [MEP,128] bf16

    unsigned short* bufE0 = bufE;                         // [MEP,512] dis / generic
    unsigned short* bufE1 = bufE + (size_t)MEP * 512;     // [MEP,512] dec

    unsigned short* pre128 = bufA;                 // enc2 out
    unsigned short* xe_bf  = bufA + (size_t)NP * 128;
    unsigned short* ZRz    = bufA + (size_t)NP * 256;   // [NP,128] z-pre
    unsigned short* hdec   = bufA;                 // [NP,512] (after GRU)
    unsigned short* RX     = x1bf;                 // [NP,128] rx (x1bf dead after conv2)
    unsigned short* outsb  = x1bf + (size_t)NP * 128;   // [NP,128] — disjoint from Greg/RX
    float* pre22 = (float*)(Greg + (size_t)NP * 128);   // [NV,2] f32 (Greg 2nd half, dead post-GRU)
    float* bufEf = (float*)bufE;

    unsigned short* wenc1 = WB;
    unsigned short* wenc2 = WB + 65536;            // [256,512] = [enc2; fc] combined
    unsigned short* wdd   = WB + 196608;           // [1024,128] = [dis1; dec1] combined
    unsigned short* wdec2 = WB + 327680;
    unsigned short* wdis2 = WB + 393216;
    unsigned short* wzr   = WB + 394240;
    unsigned short* wo    = WB + 459776;

    const int n128 = NV * 128;
    const int nScanBlocks = (NV + 255) / 256;   // 391

    auto gemm = [&](const unsigned short* A, int ldA, int ic1,
                    const unsigned short* A2, int ldA2, int ic,
                    const unsigned short* W, const float* b,
                    unsigned short* Cb, int ldb, int cb0,
                    unsigned short* Cb2, int ldb2, int splitN,
                    int oc, float* st1, float* st2, int statsC,
                    int fuse, const unsigned short* xe_p,
                    const unsigned short* zbuf, unsigned short* rxout,
                    float* oo, float* oof, unsigned short* oob) {
        dim3 g(oc / 64, NP / 128);
        mfma_gemm<<<g, 256, 0, stream>>>(A, ldA, ic1, A2, ldA2, ic, W, b,
                                         Cb, ldb, cb0, Cb2, ldb2, splitN,
                                         st1, st2, statsC, fuse, xe_p, zbuf,
                                         rxout, oo, oof, oob);
    };

    // ---- prep ----
    prep_weights<<<1931, 256, 0, stream>>>(enc1_W, enc2_W, fc_W, dis1_W, dec1_W, dec2_W, dis2_W,
                                           f1u_W, f2u_W, f1r_W, f2r_W, f1_W, f2_W,
                                           f1u_b, f2u_b, f1r_b, f2r_b, f1_b, f2_b,
                                           dis1_b, dec1_b, enc2_b, fc_b,
                                           WB, bzr, bo, bdd, bef);
    cvt_f32_bf16<<<(n128 / 4 + 255) / 256, 256, 0, stream>>>(X, Xbf, n128);

    // ---- build CSR ----
    hipMemsetAsync(deg, 0, NV * sizeof(int), stream);
    deg_kernel<<<(ME * KE + 255) / 256, 256, 0, stream>>>(vidx, deg);
    scan_block_kernel<<<nScanBlocks, 256, 0, stream>>>(deg, rowptr, bsums, NV);
    scan_sums_par<<<1, 512, 0, stream>>>(bsums, nScanBlocks);
    scan_add_kernel<<<nScanBlocks, 256, 0, stream>>>(rowptr, bsums, NV);
    hipMemcpyAsync(cursor, rowptr, NV * sizeof(int), hipMemcpyDeviceToDevice, stream);
    csr_fill_kernel<<<(ME * KE + 255) / 256, 256, 0, stream>>>(vidx, cursor, csr);

    // ================= conv1 (enc1) — cov stats + edge-domain GEMM ============
    hipMemsetAsync(sX1, 0, 256 * sizeof(float), stream);
    hipMemsetAsync(covX, 0, 16384 * sizeof(float), stream);
    colstats_bf<<<256, 256, 0, stream>>>(Xbf, sX1, sX2);
    cov_kernel<<<98, 256, 0, stream>>>(Xbf, covX);
    quadform_kernel<<<512, 128, 0, stream>>>(covX, sX1, wenc1, enc1_b, s1, s2);
    bn_finalize_pq<<<1, 512, 0, stream>>>(s1, s2, enc1_g, enc1_bt, enc1_b, scl, shf, 512, 0, 1.0f / NV);
    edge_gather_sum<<<(ME + 15) / 16, 256, 0, stream>>>(Xbf, vidx, ge);
    { dim3 g(8, MEP / 128);
      mfma_gemm_ef2<<<g, 256, 0, stream>>>(ge, wenc1, we, scl, shf, bufE0, bufE1); }
    csr_gather_bf<<<NV / 4, 256, 0, stream>>>(bufE0, 512, 0, rowptr, csr,
        nullptr, 0, x1bf, 512, 0, nullptr, 0, 512, 1);

    // ================= conv2 (enc2) + fc — merged pipelined GEMM ==============
    hipMemsetAsync(s1, 0, 2048 * sizeof(float), stream);
    gemm(x1bf, 512, 512, nullptr, 0, 512, wenc2, bef, pre128, 128, 0,
         Greg, 256, 128, 256, s1, s2, 128, 0, nullptr, nullptr, nullptr,
         nullptr, nullptr, nullptr);
    bn_finalize_kernel<<<1, 512, 0, stream>>>(s1, s2, enc2_g, enc2_bt, scl, shf, 128, 1.0f / NV);
    edge_gather_bf<<<(ME + 15) / 16, 256, 0, stream>>>(pre128, vidx, we, scl, shf, bufE0, 128);
    csr_gather_bf<<<NV / 16, 256, 0, stream>>>(bufE0, 128, 0, rowptr, csr,
        nullptr, 0, Greg, 256, 128, xe_bf, 128, 128, 0);

    // ================= GRU (fully fused into two GEMMs) =================
    gemm(Greg, 256, 256, nullptr, 0, 256, wzr, bzr, ZRz, 128, 0,
         nullptr, 0, 1 << 30, 256, nullptr, nullptr, 0,
         1, xe_bf, nullptr, RX, nullptr, nullptr, nullptr);
    gemm(Greg, 256, 128, RX, 128, 256, wo, bo, nullptr, 0, 0,
         nullptr, 0, 1 << 30, 128, nullptr, nullptr, 0,
         2, xe_bf, ZRz, nullptr, outs, nullptr, outsb);

    // ================= attention pooling -> proto (all from bf16 ws) ==========
    hipMemsetAsync(sA1, 0, 256 * sizeof(float), stream);
    colstats_bf<<<256, 256, 0, stream>>>(outsb, sA1, sA2);
    att_finalize_kernel<<<1, 128, 0, stream>>>(sA1, sA2, scl, shf, 128);
    hipMemsetAsync(proto, 0, 128 * sizeof(float), stream);
    proto_bf<<<256, 256, 0, stream>>>(outsb, scl, shf, proto);

    // ============ dis1 + dec1 — cov stats + merged edge GEMM (compact halves) ==
    hipMemsetAsync(covA, 0, 16384 * sizeof(float), stream);
    cov_kernel<<<98, 256, 0, stream>>>(outsb, covA);
    quadform_kernel<<<1024, 128, 0, stream>>>(covA, sA1, wdd, bdd, s1, s2);
    bn_finalize_pq<<<1, 512, 0, stream>>>(s1, s2, dis1_g, dis1_bt, dis1_b, scl, shf, 512, 0, 1.0f / NV);
    bn_finalize_pq<<<1, 512, 0, stream>>>(s1, s2, dec1_g, dec1_bt, dec1_b, scl, shf, 512, 512, 1.0f / NV);
    edge_gather_sum<<<(ME + 15) / 16, 256, 0, stream>>>(outsb, vidx, ge);
    { dim3 g(16, MEP / 128);
      mfma_gemm_ef2<<<g, 256, 0, stream>>>(ge, wdd, we, scl, shf, bufE0, bufE1); }
    csr_gather_dis<<<NV / 4, 256, 0, stream>>>(bufE0, rowptr, csr, wdis2, dis2_b, pre22);
    csr_gather_bf<<<NV / 4, 256, 0, stream>>>(bufE1, 512, 0, rowptr, csr,
        nullptr, 0, hdec, 512, 0, nullptr, 0, 512, 1);

    // ================= dis2 tail =================
    hipMemsetAsync(s1, 0, 2048 * sizeof(float), stream);
    colstats2_kernel<<<64, 256, 0, stream>>>(pre22, NV, s1, s2);
    bn_finalize_kernel<<<1, 512, 0, stream>>>(s1, s2, dis2_g, dis2_bt, scl, shf, 2, 1.0f / NV);
    edge_gather2_kernel<<<(ME + 255) / 256, 256, 0, stream>>>(pre22, vidx, we, scl, shf, bufEf);
    csr_gather2_kernel<<<(NV + 255) / 256, 256, 0, stream>>>(bufEf, rowptr, csr, xdis);

    // ================= dec2 (output-side conv) =================
    hipMemsetAsync(s1, 0, 2048 * sizeof(float), stream);
    gemm(hdec, 512, 512, nullptr, 0, 512, wdec2, dec2_b, Greg, 128, 0,
         nullptr, 0, 1 << 30, 128, s1, s2, 128, 0, nullptr, nullptr, nullptr,
         nullptr, nullptr, nullptr);
    bn_finalize_kernel<<<1, 512, 0, stream>>>(s1, s2, dec2_g, dec2_bt, scl, shf, 128, 1.0f / NV);
    edge_gather_bf<<<(ME + 15) / 16, 256, 0, stream>>>(Greg, vidx, we, scl, shf, bufE0, 128);
    csr_gather_bf<<<NV / 16, 256, 0, stream>>>(bufE0, 128, 0, rowptr, csr,
        x_de, 128, nullptr, 0, 0, nullptr, 0, 128, 0);
}

// Round 17
// 865.993 us; speedup vs baseline: 1.1006x; 1.1006x over previous
//
#include <hip/hip_runtime.h>
#include <cstddef>
#include <cstdint>

static constexpr int NV = 100000;   // vertices
static constexpr int NP = 100096;   // padded to 782*128
static constexpr int ME = 25000;    // hyperedges
static constexpr int MEP = 25088;   // padded to 196*128
static constexpr int KE = 16;       // vertices per edge
static constexpr float BN_EPS = 1e-5f;

typedef unsigned int u32;
typedef __attribute__((ext_vector_type(8))) short s16x8;
typedef __attribute__((ext_vector_type(8))) unsigned short u16x8;
typedef __attribute__((ext_vector_type(4))) float f32x4;

__device__ __forceinline__ float sigm(float x) { return 1.0f / (1.0f + expf(-x)); }
__device__ __forceinline__ float bf2f(unsigned short u) {
    union { u32 i; float f; } v; v.i = ((u32)u) << 16; return v.f;
}
__device__ __forceinline__ unsigned short f2bf(float f) {
    union { float f; u32 i; } v; v.f = f;
    u32 u = v.i;
    return (unsigned short)((u + 0x7FFFu + ((u >> 16) & 1u)) >> 16);
}

#define GLD16(g, l) __builtin_amdgcn_global_load_lds(                          \
    (__attribute__((address_space(1))) const unsigned int*)(g),                \
    (__attribute__((address_space(3))) unsigned int*)(l), 16, 0, 0)

// Stage A[128x64] bf16 tile into LDS buffer b (linear dest, source-swizzled
// so swizzled ds_read_b128 is conflict-free). 16 KB per buffer.
#define STAGE_A(b, k0)                                                         \
  {                                                                            \
    unsigned short* sA_ = sm + (b) * 8192;                                     \
    _Pragma("unroll")                                                          \
    for (int i_ = 0; i_ < 4; ++i_) {                                           \
      const unsigned short* g_ = A + (size_t)(bm + 32 * w + 8 * i_ + (l >> 3)) * IC + (k0) + swz; \
      GLD16(g_, sA_ + 2048 * w + 512 * i_);                                    \
    }                                                                          \
  }

// ============ pipelined bf16 MFMA GEMM: C = A[NP,IC] @ W[OC,IC]^T + bias =====
// B fragments direct from global. A double-buffered.
// XCD-chunked bijective block swizzle (m204): all column-blocks of a row-tile
// land on the same XCD so A rows are fetched once per chip.
__global__ __launch_bounds__(256)
void mfma_gemm(const unsigned short* __restrict__ A, int IC,
               const unsigned short* __restrict__ W, const float* __restrict__ bias,
               unsigned short* __restrict__ Cb, int ldb, int cb0,
               unsigned short* __restrict__ Cb2, int ldb2, int splitN,
               float* __restrict__ s1f, float* __restrict__ s2f, int statsC)
{
    __shared__ unsigned short sm[2 * 8192];   // 32 KB
    // ---- XCD-aware swizzle: flat -> vid (bijective), decode bx fastest ----
    const int BX = gridDim.x;
    const int total = BX * gridDim.y;
    const int flat = blockIdx.x + BX * blockIdx.y;
    const int q = total >> 3, r = total & 7;
    const int xcd = flat & 7, sub = flat >> 3;
    const int base = (xcd < r) ? xcd * (q + 1) : r * (q + 1) + (xcd - r) * q;
    const int vid = base + sub;
    const int bm = (vid / BX) * 128;
    const int bn = (vid % BX) * 64;

    const int tid = threadIdx.x;
    const int l = tid & 63, w = tid >> 6;
    const int wrow = w >> 1, wcol = w & 1;

    f32x4 acc[4][2];
    #pragma unroll
    for (int m = 0; m < 4; ++m)
        #pragma unroll
        for (int n = 0; n < 2; ++n)
            #pragma unroll
            for (int r2 = 0; r2 < 4; ++r2) acc[m][n][r2] = 0.f;

    const int swz = (((l & 7) ^ (l >> 3)) << 3);
    const int nt = IC >> 6;

    STAGE_A(0, 0);
    asm volatile("s_waitcnt vmcnt(0)" ::: "memory");
    __builtin_amdgcn_s_barrier();

    for (int t = 0; t < nt; ++t) {
        const int cur = t & 1;
        if (t + 1 < nt) STAGE_A(cur ^ 1, (t + 1) << 6);
        const unsigned short* sA = sm + cur * 8192;
        #pragma unroll
        for (int ks = 0; ks < 2; ++ks) {
            const int koff = ks * 32 + ((l >> 4) << 3);
            s16x8 afr[4], bfr[2];
            #pragma unroll
            for (int m = 0; m < 4; ++m) {
                int row = wrow * 64 + m * 16 + (l & 15);
                afr[m] = *(const s16x8*)&sA[row * 64 + (koff ^ ((l & 7) << 3))];
            }
            #pragma unroll
            for (int n = 0; n < 2; ++n) {
                int col = bn + wcol * 32 + n * 16 + (l & 15);
                bfr[n] = *(const s16x8*)&W[(size_t)col * IC + (t << 6) + koff];
            }
            #pragma unroll
            for (int m = 0; m < 4; ++m)
                #pragma unroll
                for (int n = 0; n < 2; ++n)
                    acc[m][n] = __builtin_amdgcn_mfma_f32_16x16x32_bf16(
                        afr[m], bfr[n], acc[m][n], 0, 0, 0);
        }
        asm volatile("s_waitcnt vmcnt(0)" ::: "memory");
        __builtin_amdgcn_s_barrier();
    }

    unsigned short* dst = Cb;
    int ld = ldb, co = cb0;
    if (Cb2 && bn >= splitN) { dst = Cb2; ld = ldb2; co = -splitN; }

    #pragma unroll
    for (int n = 0; n < 2; ++n) {
        const int col = bn + wcol * 32 + n * 16 + (l & 15);
        const float bs = bias[col];
        float ssum = 0.f, sq = 0.f;
        #pragma unroll
        for (int m = 0; m < 4; ++m) {
            const int row0 = bm + wrow * 64 + m * 16 + ((l >> 4) << 2);
            #pragma unroll
            for (int r2 = 0; r2 < 4; ++r2) {
                float v = acc[m][n][r2] + bs;
                int row = row0 + r2;
                if (dst) dst[(size_t)row * ld + co + col] = f2bf(v);
                if (s1f && col < statsC && row < NV) { ssum += v; sq += v * v; }
            }
        }
        if (s1f && col < statsC) {
            ssum += __shfl_xor(ssum, 16); ssum += __shfl_xor(ssum, 32);
            sq   += __shfl_xor(sq, 16);   sq   += __shfl_xor(sq, 32);
            if ((l >> 4) == 0) {
                atomicAdd(&s1f[col], ssum);
                atomicAdd(&s2f[col], sq);
            }
        }
    }
}

// ===== edge-domain GEMM (IC=128, B direct from global):
// ef[e,:] = we[e]*(P[c]*(ge[e,:]@W^T)[c] + Q[c]).
// Cols <512 -> ef0[e*512+c]; cols >=512 -> ef1[e*512+c-512] (compact halves).
__global__ __launch_bounds__(256)
void mfma_gemm_ef2(const unsigned short* __restrict__ A,   // ge [MEP,128]
                   const unsigned short* __restrict__ W,   // [OC,128]
                   const float* __restrict__ we,
                   const float* __restrict__ P, const float* __restrict__ Q,
                   unsigned short* __restrict__ ef0, unsigned short* __restrict__ ef1)
{
    const int IC = 128;
    __shared__ unsigned short sm[2 * 8192];
    const int bm = blockIdx.y * 128;
    const int bn = blockIdx.x * 64;
    const int tid = threadIdx.x;
    const int l = tid & 63, w = tid >> 6;
    const int wrow = w >> 1, wcol = w & 1;

    f32x4 acc[4][2];
    #pragma unroll
    for (int m = 0; m < 4; ++m)
        #pragma unroll
        for (int n = 0; n < 2; ++n)
            #pragma unroll
            for (int r = 0; r < 4; ++r) acc[m][n][r] = 0.f;

    const int swz = (((l & 7) ^ (l >> 3)) << 3);

    STAGE_A(0, 0);
    asm volatile("s_waitcnt vmcnt(0)" ::: "memory");
    __builtin_amdgcn_s_barrier();

    #pragma unroll
    for (int t = 0; t < 2; ++t) {
        const int cur = t & 1;
        if (t == 0) STAGE_A(1, 64);
        const unsigned short* sA = sm + cur * 8192;
        #pragma unroll
        for (int ks = 0; ks < 2; ++ks) {
            const int koff = ks * 32 + ((l >> 4) << 3);
            s16x8 afr[4], bfr[2];
            #pragma unroll
            for (int m = 0; m < 4; ++m) {
                int row = wrow * 64 + m * 16 + (l & 15);
                afr[m] = *(const s16x8*)&sA[row * 64 + (koff ^ ((l & 7) << 3))];
            }
            #pragma unroll
            for (int n = 0; n < 2; ++n) {
                int col = bn + wcol * 32 + n * 16 + (l & 15);
                bfr[n] = *(const s16x8*)&W[(size_t)col * 128 + (t << 6) + koff];
            }
            #pragma unroll
            for (int m = 0; m < 4; ++m)
                #pragma unroll
                for (int n = 0; n < 2; ++n)
                    acc[m][n] = __builtin_amdgcn_mfma_f32_16x16x32_bf16(
                        afr[m], bfr[n], acc[m][n], 0, 0, 0);
        }
        asm volatile("s_waitcnt vmcnt(0)" ::: "memory");
        __builtin_amdgcn_s_barrier();
    }

    unsigned short* dst = (bn < 512) ? ef0 : ef1;
    const int co = (bn < 512) ? 0 : -512;

    #pragma unroll
    for (int n = 0; n < 2; ++n) {
        const int colg = bn + wcol * 32 + n * 16 + (l & 15);
        const float pc = P[colg], qc = Q[colg];
        #pragma unroll
        for (int m = 0; m < 4; ++m) {
            const int row0 = bm + wrow * 64 + m * 16 + ((l >> 4) << 2);
            #pragma unroll
            for (int r = 0; r < 4; ++r) {
                int row = row0 + r;
                if (row < ME) {
                    float wv = we[row];
                    dst[(size_t)row * 512 + co + colg] = f2bf(wv * (pc * acc[m][n][r] + qc));
                }
            }
        }
    }
}

// ===== covariance: cov[i][j] = sum_{v<NV} A[v,i]*A[v,j]  (A bf16 [NP,128]) ====
__global__ __launch_bounds__(256)
void cov_kernel(const unsigned short* __restrict__ A, float* __restrict__ cov)
{
    __shared__ unsigned short T[128 * 64];
    const int tid = threadIdx.x;
    const int l = tid & 63, w = tid >> 6;

    f32x4 acc[2][8];
    #pragma unroll
    for (int m = 0; m < 2; ++m)
        #pragma unroll
        for (int n = 0; n < 8; ++n)
            #pragma unroll
            for (int r = 0; r < 4; ++r) acc[m][n][r] = 0.f;

    const int r0 = blockIdx.x * 1024;
    for (int ch = 0; ch < 16; ++ch) {
        const int rbase = r0 + ch * 64;
        __syncthreads();
        #pragma unroll
        for (int q = 0; q < 4; ++q) {
            int idx = tid + q * 256;
            int r = idx & 63, cg = idx >> 6;
            int row = rbase + r;
            u16x8 u = {0, 0, 0, 0, 0, 0, 0, 0};
            if (row < NV) u = *(const u16x8*)&A[(size_t)row * 128 + cg * 8];
            #pragma unroll
            for (int j = 0; j < 8; ++j) {
                int c = cg * 8 + j;
                T[c * 64 + (r ^ ((c & 7) << 3))] = u[j];
            }
        }
        __syncthreads();
        #pragma unroll
        for (int ks = 0; ks < 2; ++ks) {
            const int koff = ks * 32 + ((l >> 4) << 3);
            s16x8 fi[2], fj[8];
            #pragma unroll
            for (int m = 0; m < 2; ++m) {
                int c = (w * 2 + m) * 16 + (l & 15);
                fi[m] = *(const s16x8*)&T[c * 64 + (koff ^ ((c & 7) << 3))];
            }
            #pragma unroll
            for (int n = 0; n < 8; ++n) {
                int c = n * 16 + (l & 15);
                fj[n] = *(const s16x8*)&T[c * 64 + (koff ^ ((c & 7) << 3))];
            }
            #pragma unroll
            for (int m = 0; m < 2; ++m)
                #pragma unroll
                for (int n = 0; n < 8; ++n)
                    acc[m][n] = __builtin_amdgcn_mfma_f32_16x16x32_bf16(
                        fi[m], fj[n], acc[m][n], 0, 0, 0);
        }
    }
    #pragma unroll
    for (int m = 0; m < 2; ++m) {
        #pragma unroll
        for (int n = 0; n < 8; ++n) {
            #pragma unroll
            for (int r = 0; r < 4; ++r) {
                int row = (w * 2 + m) * 16 + ((l >> 4) << 2) + r;
                int col = n * 16 + (l & 15);
                atomicAdd(&cov[row * 128 + col], acc[m][n][r]);
            }
        }
    }
}

// ===== BN stats from covariance ==============================================
__global__ __launch_bounds__(128)
void quadform_kernel(const float* __restrict__ cov, const float* __restrict__ colsum,
                     const unsigned short* __restrict__ Wt, const float* __restrict__ bias,
                     float* __restrict__ s1, float* __restrict__ s2)
{
    const int c = blockIdx.x, i = threadIdx.x;
    __shared__ float wv[128];
    __shared__ float red[128][2];
    float wi = bf2f(Wt[c * 128 + i]);
    wv[i] = wi;
    __syncthreads();
    const float* crow = cov + i * 128;
    float dot = 0.f;
    #pragma unroll 8
    for (int j = 0; j < 128; ++j) dot += crow[j] * wv[j];
    red[i][0] = wi * dot;
    red[i][1] = wi * colsum[i];
    __syncthreads();
    for (int s = 64; s > 0; s >>= 1) {
        if (i < s) { red[i][0] += red[i + s][0]; red[i][1] += red[i + s][1]; }
        __syncthreads();
    }
    if (i == 0) {
        float b = bias[c];
        float ws = red[0][1];
        s1[c] = ws + (float)NV * b;
        s2[c] = red[0][0] + 2.f * b * ws + (float)NV * b * b;
    }
}

// ================= weight prep ================================================
__global__ void prep_weights(const float* e1, const float* e2, const float* fcw,
                             const float* d1, const float* dc1, const float* dc2,
                             const float* ds2,
                             const float* f1u, const float* f2u,
                             const float* f1r, const float* f2r,
                             const float* f1, const float* f2,
                             const float* f1ub, const float* f2ub,
                             const float* f1rb, const float* f2rb,
                             const float* f1b, const float* f2b,
                             const float* ds1b, const float* dc1b,
                             const float* e2b, const float* fcb,
                             unsigned short* WB, float* bzr, float* bo,
                             float* bdd, float* bef)
{
    int i = blockIdx.x * 256 + threadIdx.x;
    if (i < 65536)           WB[i] = f2bf(e1[i]);
    else if (i < 131072)     WB[i] = f2bf(e2[i - 65536]);
    else if (i < 196608)     WB[i] = f2bf(fcw[i - 131072]);
    else if (i < 262144)     WB[i] = f2bf(d1[i - 196608]);
    else if (i < 327680)     WB[i] = f2bf(dc1[i - 262144]);
    else if (i < 393216)     WB[i] = f2bf(dc2[i - 327680]);
    else if (i < 394240)     WB[i] = f2bf(ds2[i - 393216]);
    else if (i < 459776) {
        int j = i - 394240, row = j >> 8, c = j & 255;
        float v;
        if (row < 128) v = (c < 128) ? f1u[row * 128 + c] : f2u[row * 128 + c - 128];
        else { int rr = row - 128; v = (c < 128) ? f1r[rr * 128 + c] : f2r[rr * 128 + c - 128]; }
        WB[i] = f2bf(v);
    } else if (i < 492544) {
        int j = i - 459776, row = j >> 8, c = j & 255;
        float v = (c < 128) ? f1[row * 128 + c] : f2[row * 128 + c - 128];
        WB[i] = f2bf(v);
    } else if (i < 492800) {
        int o = i - 492544;
        bzr[o] = (o < 128) ? (f1ub[o] + f2ub[o]) : (f1rb[o - 128] + f2rb[o - 128]);
    } else if (i < 492928) {
        int o = i - 492800;
        bo[o] = f1b[o] + f2b[o];
    } else if (i < 493952) {
        int o = i - 492928;
        bdd[o] = (o < 512) ? ds1b[o] : dc1b[o - 512];
    } else if (i < 494208) {
        int o = i - 493952;
        bef[o] = (o < 128) ? e2b[o] : fcb[o - 128];
    }
}

__global__ void cvt_f32_bf16(const float* __restrict__ in, unsigned short* __restrict__ out, int n)
{
    int i = (blockIdx.x * 256 + threadIdx.x) * 4;
    if (i < n) {
        float4 v = *reinterpret_cast<const float4*>(&in[i]);
        out[i] = f2bf(v.x); out[i + 1] = f2bf(v.y);
        out[i + 2] = f2bf(v.z); out[i + 3] = f2bf(v.w);
    }
}

// ================= BN finalize (scale/shift form, output-side convs) ==========
__global__ void bn_finalize_kernel(const float* __restrict__ s1, const float* __restrict__ s2,
                                   const float* __restrict__ g, const float* __restrict__ bt,
                                   float* __restrict__ scale, float* __restrict__ shift,
                                   int C, float invN)
{
    int c = threadIdx.x;
    if (c < C) {
        float m = s1[c] * invN;
        float v = fmaxf(s2[c] * invN - m * m, 0.f);
        float sc = g[c] * rsqrtf(v + BN_EPS);
        scale[c] = sc;
        shift[c] = bt[c] - m * sc;
    }
}

// ===== BN finalize (P/Q form, edge-domain convs): P=scale/K, Q=scale*b+shift ==
__global__ void bn_finalize_pq(const float* __restrict__ s1, const float* __restrict__ s2,
                               const float* __restrict__ g, const float* __restrict__ bt,
                               const float* __restrict__ bias,
                               float* __restrict__ P, float* __restrict__ Q,
                               int C, int off, float invN)
{
    int c = threadIdx.x;
    if (c < C) {
        int cc = off + c;
        float m = s1[cc] * invN;
        float v = fmaxf(s2[cc] * invN - m * m, 0.f);
        float sc = g[c] * rsqrtf(v + BN_EPS);
        float sh = bt[c] - m * sc;
        P[cc] = sc * (1.0f / KE);
        Q[cc] = sc * bias[c] + sh;
    }
}

// ========== edge gather of raw input: ge[e,c] = sum_k x[v_k,c] ================
__global__ __launch_bounds__(256)
void edge_gather_sum(const unsigned short* __restrict__ x, const int* __restrict__ vidx,
                     unsigned short* __restrict__ ge)
{
    const int e = blockIdx.x * 16 + (threadIdx.x >> 4);
    const int cp = (threadIdx.x & 15) << 3;
    if (e >= ME) return;
    float s[8] = {};
    const int* vi = vidx + e * KE;
    #pragma unroll
    for (int k = 0; k < KE; ++k) {
        int v = vi[k];
        u16x8 u = *(const u16x8*)&x[(size_t)v * 128 + cp];
        #pragma unroll
        for (int j = 0; j < 8; ++j) s[j] += bf2f(u[j]);
    }
    u16x8 o;
    #pragma unroll
    for (int j = 0; j < 8; ++j) o[j] = f2bf(s[j]);
    *(u16x8*)&ge[(size_t)e * 128 + cp] = o;
}

// ========== edge gather (bf16, fused BN), output-side convs (C=128) ===========
__global__ __launch_bounds__(256)
void edge_gather_bf(const unsigned short* __restrict__ pre, const int* __restrict__ vidx,
                    const float* __restrict__ we, const float* __restrict__ scl,
                    const float* __restrict__ shf, unsigned short* __restrict__ ef, int C)
{
    const int tpe = C >> 3;
    const int epb = 256 / tpe;
    const int e = blockIdx.x * epb + threadIdx.x / tpe;
    const int cp = (threadIdx.x % tpe) << 3;
    if (e >= ME) return;
    float s[8] = {};
    const int* vi = vidx + e * KE;
    #pragma unroll
    for (int k = 0; k < KE; ++k) {
        int v = vi[k];
        u16x8 u = *(const u16x8*)&pre[(size_t)v * C + cp];
        #pragma unroll
        for (int j = 0; j < 8; ++j) s[j] += bf2f(u[j]);
    }
    float wv = we[e] * (1.0f / KE);
    u16x8 o;
    #pragma unroll
    for (int j = 0; j < 8; ++j)
        o[j] = f2bf(wv * (scl[cp + j] * s[j] + (float)KE * shf[cp + j]));
    *(u16x8*)&ef[(size_t)e * C + cp] = o;
}

// f32 variant for C == 2 (dis2 path)
__global__ void edge_gather2_kernel(const float* __restrict__ X, const int* __restrict__ vidx,
                                    const float* __restrict__ we, const float* __restrict__ scale,
                                    const float* __restrict__ shift, float* __restrict__ ef)
{
    int e = blockIdx.x * blockDim.x + threadIdx.x;
    if (e >= ME) return;
    float s0 = 0.f, s1v = 0.f;
    #pragma unroll
    for (int k = 0; k < KE; ++k) {
        int v = vidx[e * KE + k];
        s0 += X[2 * v];
        s1v += X[2 * v + 1];
    }
    float w = we[e] * (1.0f / KE);
    ef[2 * e]     = w * (scale[0] * s0 + (float)KE * shift[0]);
    ef[2 * e + 1] = w * (scale[1] * s1v + (float)KE * shift[1]);
}

// ================= CSR build ===================================================
__global__ void deg_kernel(const int* __restrict__ vidx, int* __restrict__ deg)
{
    int i = blockIdx.x * blockDim.x + threadIdx.x;
    if (i < ME * KE) atomicAdd(&deg[vidx[i]], 1);
}

__global__ void scan_block_kernel(const int* __restrict__ deg, int* __restrict__ rowptr,
                                  int* __restrict__ blocksums, int n)
{
    __shared__ int tmp[256];
    int i = blockIdx.x * 256 + threadIdx.x;
    int v = (i < n) ? deg[i] : 0;
    tmp[threadIdx.x] = v;
    __syncthreads();
    for (int off = 1; off < 256; off <<= 1) {
        int t = (threadIdx.x >= off) ? tmp[threadIdx.x - off] : 0;
        __syncthreads();
        tmp[threadIdx.x] += t;
        __syncthreads();
    }
    if (i < n) rowptr[i] = tmp[threadIdx.x] - v;
    if (threadIdx.x == 255) blocksums[blockIdx.x] = tmp[255];
}

__global__ void scan_sums_par(int* __restrict__ bs, int nb)
{
    __shared__ int tmp[512];
    int t = threadIdx.x;
    int v = (t < nb) ? bs[t] : 0;
    tmp[t] = v;
    __syncthreads();
    for (int off = 1; off < 512; off <<= 1) {
        int u = (t >= off) ? tmp[t - off] : 0;
        __syncthreads();
        tmp[t] += u;
        __syncthreads();
    }
    if (t < nb) bs[t] = tmp[t] - v;
}

__global__ void scan_add_kernel(int* __restrict__ rowptr, const int* __restrict__ blocksums, int n)
{
    int i = blockIdx.x * 256 + threadIdx.x;
    if (i < n) rowptr[i] += blocksums[blockIdx.x];
    if (i == 0) rowptr[n] = ME * KE;
}

__global__ void csr_fill_kernel(const int* __restrict__ vidx, int* __restrict__ cursor,
                                int* __restrict__ csr)
{
    int i = blockIdx.x * blockDim.x + threadIdx.x;
    if (i < ME * KE) {
        int v = vidx[i];
        int pos = atomicAdd(&cursor[v], 1);
        csr[pos] = i >> 4;
    }
}

// ===== e->v via CSR gather (bf16 ef rows, stride ldE, col offset cb0E) ========
__global__ __launch_bounds__(256)
void csr_gather_bf(const unsigned short* __restrict__ ef, int ldE, int cb0E,
                   const int* __restrict__ rowptr, const int* __restrict__ csr,
                   float* __restrict__ outf, int ldf,
                   unsigned short* __restrict__ outb, int ldb, int cb0,
                   unsigned short* __restrict__ outb2, int ldb2,
                   int C, int relu)
{
    const int lpv = C >> 3;
    const int vpb = 256 / lpv;
    const int v = blockIdx.x * vpb + threadIdx.x / lpv;
    const int lg = threadIdx.x % lpv;
    if (v >= NV) return;
    const int s = rowptr[v], e = rowptr[v + 1];
    float a[8] = {};
    int i = s;
    for (; i + 2 <= e; i += 2) {
        int e0 = csr[i], e1 = csr[i + 1];
        u16x8 u0 = *(const u16x8*)&ef[(size_t)e0 * ldE + cb0E + lg * 8];
        u16x8 u1 = *(const u16x8*)&ef[(size_t)e1 * ldE + cb0E + lg * 8];
        #pragma unroll
        for (int j = 0; j < 8; ++j) a[j] += bf2f(u0[j]) + bf2f(u1[j]);
    }
    if (i < e) {
        int e0 = csr[i];
        u16x8 u0 = *(const u16x8*)&ef[(size_t)e0 * ldE + cb0E + lg * 8];
        #pragma unroll
        for (int j = 0; j < 8; ++j) a[j] += bf2f(u0[j]);
    }
    float inv = 1.0f / (float)max(e - s, 1);
    #pragma unroll
    for (int j = 0; j < 8; ++j) {
        float x = a[j] * inv;
        if (relu) x = fmaxf(x, 0.f);
        a[j] = x;
    }
    if (outf) {
        float* p = outf + (size_t)v * ldf + lg * 8;
        #pragma unroll
        for (int j = 0; j < 8; ++j) p[j] = a[j];
    }
    if (outb) {
        u16x8 o;
        #pragma unroll
        for (int j = 0; j < 8; ++j) o[j] = f2bf(a[j]);
        *(u16x8*)&outb[(size_t)v * ldb + cb0 + lg * 8] = o;
    }
    if (outb2) {
        u16x8 o;
        #pragma unroll
        for (int j = 0; j < 8; ++j) o[j] = f2bf(a[j]);
        *(u16x8*)&outb2[(size_t)v * ldb2 + lg * 8] = o;
    }
}

// ===== dis-half gather: aggregate hdis row (relu) and dot with wdis2 ->
// pre22 directly (in-wave 64-lane reduce, no atomics).
__global__ __launch_bounds__(256)
void csr_gather_dis(const unsigned short* __restrict__ ef,   // [MEP,512] dis half
                    const int* __restrict__ rowptr, const int* __restrict__ csr,
                    const unsigned short* __restrict__ wdis2, const float* __restrict__ dis2b,
                    float* __restrict__ pre22)
{
    const int w = threadIdx.x >> 6, l = threadIdx.x & 63;
    const int v = blockIdx.x * 4 + w;
    if (v >= NV) return;
    const int s = rowptr[v], e = rowptr[v + 1];
    float a[8] = {};
    int i = s;
    for (; i + 2 <= e; i += 2) {
        int e0 = csr[i], e1 = csr[i + 1];
        u16x8 u0 = *(const u16x8*)&ef[(size_t)e0 * 512 + l * 8];
        u16x8 u1 = *(const u16x8*)&ef[(size_t)e1 * 512 + l * 8];
        #pragma unroll
        for (int j = 0; j < 8; ++j) a[j] += bf2f(u0[j]) + bf2f(u1[j]);
    }
    if (i < e) {
        int e0 = csr[i];
        u16x8 u0 = *(const u16x8*)&ef[(size_t)e0 * 512 + l * 8];
        #pragma unroll
        for (int j = 0; j < 8; ++j) a[j] += bf2f(u0[j]);
    }
    float inv = 1.0f / (float)max(e - s, 1);
    u16x8 w0 = *(const u16x8*)&wdis2[l * 8];
    u16x8 w1 = *(const u16x8*)&wdis2[512 + l * 8];
    float d0 = 0.f, d1 = 0.f;
    #pragma unroll
    for (int j = 0; j < 8; ++j) {
        float h = fmaxf(a[j] * inv, 0.f);
        d0 += h * bf2f(w0[j]);
        d1 += h * bf2f(w1[j]);
    }
    for (int o = 32; o > 0; o >>= 1) {
        d0 += __shfl_down(d0, o);
        d1 += __shfl_down(d1, o);
    }
    if (l == 0) {
        pre22[2 * v]     = d0 + dis2b[0];
        pre22[2 * v + 1] = d1 + dis2b[1];
    }
}

__global__ void csr_gather2_kernel(const float* __restrict__ ef, const int* __restrict__ rowptr,
                                   const int* __restrict__ csr, float* __restrict__ outp)
{
    int v = blockIdx.x * blockDim.x + threadIdx.x;
    if (v >= NV) return;
    int s = rowptr[v], e = rowptr[v + 1];
    float a0 = 0.f, a1 = 0.f;
    for (int i = s; i < e; ++i) {
        int ed = csr[i];
        a0 += ef[2 * ed];
        a1 += ef[2 * ed + 1];
    }
    float inv = 1.0f / (float)max(e - s, 1);
    outp[2 * v]     = a0 * inv;
    outp[2 * v + 1] = a1 * inv;
}

// ========== column stats over bf16 [NP,128] ws buffer =========================
__global__ __launch_bounds__(256)
void colstats_bf(const unsigned short* __restrict__ Xb,
                 float* __restrict__ s1, float* __restrict__ s2)
{
    const int t = threadIdx.x;
    const int cg = t & 15;
    const int rs = t >> 4;
    float s[8] = {}, q[8] = {};
    for (int r = blockIdx.x * 16 + rs; r < NV; r += 256 * 16) {
        u16x8 u = *(const u16x8*)&Xb[(size_t)r * 128 + cg * 8];
        #pragma unroll
        for (int j = 0; j < 8; ++j) {
            float v = bf2f(u[j]);
            s[j] += v; q[j] += v * v;
        }
    }
    __shared__ float ls[16][16][8];
    __shared__ float lq[16][16][8];
    #pragma unroll
    for (int j = 0; j < 8; ++j) { ls[rs][cg][j] = s[j]; lq[rs][cg][j] = q[j]; }
    __syncthreads();
    int c = t & 127;
    float a = 0.f;
    if (t < 128) {
        #pragma unroll
        for (int i = 0; i < 16; ++i) a += ls[i][c >> 3][c & 7];
        atomicAdd(&s1[c], a);
    } else {
        #pragma unroll
        for (int i = 0; i < 16; ++i) a += lq[i][c >> 3][c & 7];
        atomicAdd(&s2[c], a);
    }
}

__global__ void att_finalize_kernel(const float* __restrict__ s1, const float* __restrict__ s2,
                                    float* __restrict__ mu, float* __restrict__ qd, int C)
{
    int c = threadIdx.x;
    if (c < C) {
        float m = s1[c] / (float)NV;
        float vv = fmaxf((s2[c] - (float)NV * m * m) / (float)(NV - 1), 0.f);
        mu[c] = m;
        qd[c] = 1.0f / (4.0f * (vv + 0.001f));
    }
}

// ========== proto over outsb (bf16 ws), grid-stride + LDS reduce ==============
__global__ __launch_bounds__(256)
void proto_bf(const unsigned short* __restrict__ Xb, const float* __restrict__ mu,
              const float* __restrict__ qd, float* __restrict__ proto)
{
    const int t = threadIdx.x;
    const int cg = t & 15;
    const int rs = t >> 4;
    float m[8], q[8], a[8] = {};
    #pragma unroll
    for (int j = 0; j < 8; ++j) { m[j] = mu[cg * 8 + j]; q[j] = qd[cg * 8 + j]; }
    for (int r = blockIdx.x * 16 + rs; r < NV; r += 256 * 16) {
        u16x8 u = *(const u16x8*)&Xb[(size_t)r * 128 + cg * 8];
        #pragma unroll
        for (int j = 0; j < 8; ++j) {
            float x = bf2f(u[j]);
            float d = x - m[j];
            a[j] += x * sigm(d * d * q[j] + 0.5f);
        }
    }
    __shared__ float ls[16][16][8];
    #pragma unroll
    for (int j = 0; j < 8; ++j) ls[rs][cg][j] = a[j];
    __syncthreads();
    if (t < 128) {
        float acc = 0.f;
        #pragma unroll
        for (int i = 0; i < 16; ++i) acc += ls[i][t >> 3][t & 7];
        atomicAdd(&proto[t], acc);
    }
}

// ================= stats for C==2 ==============================================
__global__ void colstats2_kernel(const float* __restrict__ X, int N,
                                 float* __restrict__ s1, float* __restrict__ s2)
{
    __shared__ float red[256][4];
    int t = threadIdx.x;
    float a0 = 0, a1 = 0, b0 = 0, b1 = 0;
    for (int r = blockIdx.x * 256 + t; r < N; r += 256 * gridDim.x) {
        float x0 = X[2 * r], x1 = X[2 * r + 1];
        a0 += x0; b0 += x0 * x0;
        a1 += x1; b1 += x1 * x1;
    }
    red[t][0] = a0; red[t][1] = a1; red[t][2] = b0; red[t][3] = b1;
    __syncthreads();
    for (int s = 128; s > 0; s >>= 1) {
        if (t < s)
            for (int j = 0; j < 4; ++j) red[t][j] += red[t + s][j];
        __syncthreads();
    }
    if (t == 0) {
        atomicAdd(&s1[0], red[0][0]);
        atomicAdd(&s1[1], red[0][1]);
        atomicAdd(&s2[0], red[0][2]);
        atomicAdd(&s2[1], red[0][3]);
    }
}

// ================= GRU elementwise (vectorized u16x8) ==========================
__global__ void rx_kernel(const unsigned short* __restrict__ ZR, const unsigned short* __restrict__ xeb,
                          unsigned short* __restrict__ G, int n8)
{
    int idx = blockIdx.x * blockDim.x + threadIdx.x;
    if (idx >= n8) return;
    int i8 = idx * 8;
    int row = i8 >> 7, c = i8 & 127;
    u16x8 rv = *(const u16x8*)&ZR[(size_t)row * 256 + 128 + c];
    u16x8 xv = *(const u16x8*)&xeb[i8];
    u16x8 g;
    #pragma unroll
    for (int j = 0; j < 8; ++j)
        g[j] = f2bf(sigm(bf2f(rv[j])) * bf2f(xv[j]));
    *(u16x8*)&G[(size_t)row * 256 + 128 + c] = g;
}

__global__ void gru_out_kernel(const unsigned short* __restrict__ ZR, const unsigned short* __restrict__ Opre,
                               const unsigned short* __restrict__ xeb,
                               float* __restrict__ outs, unsigned short* __restrict__ outsb, int n8)
{
    int idx = blockIdx.x * blockDim.x + threadIdx.x;
    if (idx >= n8) return;
    int i8 = idx * 8;
    int row = i8 >> 7, c = i8 & 127;
    u16x8 zv = *(const u16x8*)&ZR[(size_t)row * 256 + c];
    u16x8 ov = *(const u16x8*)&Opre[i8];
    u16x8 xv = *(const u16x8*)&xeb[i8];
    float val[8];
    u16x8 ob;
    #pragma unroll
    for (int j = 0; j < 8; ++j) {
        float z = sigm(bf2f(zv[j]));
        float o = tanhf(bf2f(ov[j]));
        float xe = bf2f(xv[j]);
        val[j] = z * o + (1.f - z) * xe;
        ob[j] = f2bf(val[j]);
    }
    *(float4*)&outs[i8]     = make_float4(val[0], val[1], val[2], val[3]);
    *(float4*)&outs[i8 + 4] = make_float4(val[4], val[5], val[6], val[7]);
    *(u16x8*)&outsb[i8] = ob;
}

// ==============================================================================
extern "C" void kernel_launch(void* const* d_in, const int* in_sizes, int n_in,
                              void* d_out, int out_size, void* d_ws, size_t ws_size,
                              hipStream_t stream)
{
    const float* X      = (const float*)d_in[0];
    const int*   vidx   = (const int*)  d_in[1];
    const float* we     = (const float*)d_in[2];
    const float* enc1_W = (const float*)d_in[3];  const float* enc1_b = (const float*)d_in[4];
    const float* enc2_W = (const float*)d_in[5];  const float* enc2_b = (const float*)d_in[6];
    const float* fc_W   = (const float*)d_in[7];  const float* fc_b   = (const float*)d_in[8];
    const float* f1u_W  = (const float*)d_in[9];  const float* f1u_b  = (const float*)d_in[10];
    const float* f2u_W  = (const float*)d_in[11]; const float* f2u_b  = (const float*)d_in[12];
    const float* f1r_W  = (const float*)d_in[13]; const float* f1r_b  = (const float*)d_in[14];
    const float* f2r_W  = (const float*)d_in[15]; const float* f2r_b  = (const float*)d_in[16];
    const float* f1_W   = (const float*)d_in[17]; const float* f1_b   = (const float*)d_in[18];
    const float* f2_W   = (const float*)d_in[19]; const float* f2_b   = (const float*)d_in[20];
    const float* dis1_W = (const float*)d_in[21]; const float* dis1_b = (const float*)d_in[22];
    const float* dis2_W = (const float*)d_in[23]; const float* dis2_b = (const float*)d_in[24];
    const float* dec1_W = (const float*)d_in[25]; const float* dec1_b = (const float*)d_in[26];
    const float* dec2_W = (const float*)d_in[27]; const float* dec2_b = (const float*)d_in[28];
    const float* enc1_g = (const float*)d_in[29]; const float* enc1_bt = (const float*)d_in[30];
    const float* enc2_g = (const float*)d_in[31]; const float* enc2_bt = (const float*)d_in[32];
    const float* dis1_g = (const float*)d_in[33]; const float* dis1_bt = (const float*)d_in[34];
    const float* dis2_g = (const float*)d_in[35]; const float* dis2_bt = (const float*)d_in[36];
    const float* dec1_g = (const float*)d_in[37]; const float* dec1_bt = (const float*)d_in[38];
    const float* dec2_g = (const float*)d_in[39]; const float* dec2_bt = (const float*)d_in[40];

    float* out   = (float*)d_out;
    float* outs  = out;                   // [N,128]
    float* x_de  = out + 12800000;        // [N,128]
    float* proto = out + 25600000;        // [128]
    float* xdis  = out + 25600128;        // [N,2]

    // ---------------- workspace layout ----------------
    char* base = (char*)d_ws;
    unsigned short* bufA = (unsigned short*)base;                 // [NP,512] bf16
    char* p = base + (size_t)NP * 512 * 2;
    unsigned short* bufE = (unsigned short*)p; p += (size_t)MEP * 1024 * 2;   // 2x [MEP,512]
    unsigned short* Greg = (unsigned short*)p;                    // [NP,256] bf16
    unsigned short* Xbf  = Greg;                                  // [NP,128]
    unsigned short* outsb = Greg + (size_t)NP * 128;              // [NP,128]
    p += (size_t)NP * 256 * 2;
    unsigned short* x1bf = (unsigned short*)p; p += (size_t)NP * 512 * 2;
    unsigned short* WB = (unsigned short*)p; p += 492544 * 2 + 1024;
    float* bzr = (float*)p; p += 256 * 4;
    float* bo  = (float*)p; p += 128 * 4;
    float* bdd = (float*)p; p += 1024 * 4;
    float* bef = (float*)p; p += 256 * 4;
    float* s1  = (float*)p; p += 1024 * 4;
    float* s2  = (float*)p; p += 1024 * 4;
    float* scl = (float*)p; p += 1024 * 4;   // also P
    float* shf = (float*)p; p += 1024 * 4;   // also Q
    float* sX1 = (float*)p; p += 128 * 4;
    float* sX2 = (float*)p; p += 128 * 4;
    float* sA1 = (float*)p; p += 128 * 4;
    float* sA2 = (float*)p; p += 128 * 4;
    float* covX = (float*)p; p += 16384 * 4;
    float* covA = (float*)p; p += 16384 * 4;
    int* deg    = (int*)p; p += (size_t)NV * 4;
    int* rowptr = (int*)p; p += (size_t)(NV + 1) * 4;
    int* cursor = (int*)p; p += (size_t)NV * 4;
    int* bsums  = (int*)p; p += 512 * 4;
    int* csr    = (int*)p; p += (size_t)ME * KE * 4;
    unsigned short* ge = (unsigned short*)p;                      // [MEP,128] bf16

    unsigned short* bufE0 = bufE;                         // [MEP,512] dis / generic
    unsigned short* bufE1 = bufE + (size_t)MEP * 512;     // [MEP,512] dec

    unsigned short* pre128 = bufA;                 // enc2 out / Opre
    unsigned short* xe_bf  = bufA + (size_t)NP * 128;
    unsigned short* ZR     = bufA + (size_t)NP * 256;
    unsigned short* Opre   = bufA;
    unsigned short* hdec   = bufA;                 // [NP,512] (after GRU)
    float* pre22 = (float*)(Greg + (size_t)NP * 128);  // [NV,2] f32 (outsb region, dead by then)
    float* bufEf = (float*)bufE;

    unsigned short* wenc1 = WB;
    unsigned short* wenc2 = WB + 65536;            // [256,512] = [enc2; fc] combined
    unsigned short* wdd   = WB + 196608;           // [1024,128] = [dis1; dec1] combined
    unsigned short* wdec2 = WB + 327680;
    unsigned short* wdis2 = WB + 393216;
    unsigned short* wzr   = WB + 394240;
    unsigned short* wo    = WB + 459776;

    const int n128 = NV * 128;
    const int n8 = n128 / 8;
    const int nScanBlocks = (NV + 255) / 256;   // 391

    auto gemm = [&](const unsigned short* A, int ic, const unsigned short* W, const float* b,
                    unsigned short* Cb, int ldb, int cb0,
                    unsigned short* Cb2, int ldb2, int splitN,
                    int oc, float* st1, float* st2, int statsC) {
        dim3 g(oc / 64, NP / 128);
        mfma_gemm<<<g, 256, 0, stream>>>(A, ic, W, b, Cb, ldb, cb0, Cb2, ldb2, splitN,
                                         st1, st2, statsC);
    };

    // ---- prep ----
    prep_weights<<<1931, 256, 0, stream>>>(enc1_W, enc2_W, fc_W, dis1_W, dec1_W, dec2_W, dis2_W,
                                           f1u_W, f2u_W, f1r_W, f2r_W, f1_W, f2_W,
                                           f1u_b, f2u_b, f1r_b, f2r_b, f1_b, f2_b,
                                           dis1_b, dec1_b, enc2_b, fc_b,
                                           WB, bzr, bo, bdd, bef);
    cvt_f32_bf16<<<(n128 / 4 + 255) / 256, 256, 0, stream>>>(X, Xbf, n128);

    // ---- build CSR ----
    hipMemsetAsync(deg, 0, NV * sizeof(int), stream);
    deg_kernel<<<(ME * KE + 255) / 256, 256, 0, stream>>>(vidx, deg);
    scan_block_kernel<<<nScanBlocks, 256, 0, stream>>>(deg, rowptr, bsums, NV);
    scan_sums_par<<<1, 512, 0, stream>>>(bsums, nScanBlocks);
    scan_add_kernel<<<nScanBlocks, 256, 0, stream>>>(rowptr, bsums, NV);
    hipMemcpyAsync(cursor, rowptr, NV * sizeof(int), hipMemcpyDeviceToDevice, stream);
    csr_fill_kernel<<<(ME * KE + 255) / 256, 256, 0, stream>>>(vidx, cursor, csr);

    // ================= conv1 (enc1) — cov stats + edge-domain GEMM ============
    hipMemsetAsync(sX1, 0, 256 * sizeof(float), stream);
    hipMemsetAsync(covX, 0, 16384 * sizeof(float), stream);
    colstats_bf<<<256, 256, 0, stream>>>(Xbf, sX1, sX2);
    cov_kernel<<<98, 256, 0, stream>>>(Xbf, covX);
    quadform_kernel<<<512, 128, 0, stream>>>(covX, sX1, wenc1, enc1_b, s1, s2);
    bn_finalize_pq<<<1, 512, 0, stream>>>(s1, s2, enc1_g, enc1_bt, enc1_b, scl, shf, 512, 0, 1.0f / NV);
    edge_gather_sum<<<(ME + 15) / 16, 256, 0, stream>>>(Xbf, vidx, ge);
    { dim3 g(8, MEP / 128);
      mfma_gemm_ef2<<<g, 256, 0, stream>>>(ge, wenc1, we, scl, shf, bufE0, bufE1); }
    csr_gather_bf<<<NV / 4, 256, 0, stream>>>(bufE0, 512, 0, rowptr, csr,
        nullptr, 0, x1bf, 512, 0, nullptr, 0, 512, 1);

    // ================= conv2 (enc2) + fc — merged pipelined GEMM ==============
    hipMemsetAsync(s1, 0, 2048 * sizeof(float), stream);
    gemm(x1bf, 512, wenc2, bef, pre128, 128, 0, Greg, 256, 128, 256, s1, s2, 128);
    bn_finalize_kernel<<<1, 512, 0, stream>>>(s1, s2, enc2_g, enc2_bt, scl, shf, 128, 1.0f / NV);
    edge_gather_bf<<<(ME + 15) / 16, 256, 0, stream>>>(pre128, vidx, we, scl, shf, bufE0, 128);
    csr_gather_bf<<<NV / 16, 256, 0, stream>>>(bufE0, 128, 0, rowptr, csr,
        nullptr, 0, Greg, 256, 128, xe_bf, 128, 128, 0);

    // ================= GRU =================
    gemm(Greg, 256, wzr, bzr, ZR, 256, 0, nullptr, 0, 1 << 30, 256, nullptr, nullptr, 0);
    rx_kernel<<<(n8 + 255) / 256, 256, 0, stream>>>(ZR, xe_bf, Greg, n8);
    gemm(Greg, 256, wo, bo, Opre, 128, 0, nullptr, 0, 1 << 30, 128, nullptr, nullptr, 0);
    gru_out_kernel<<<(n8 + 255) / 256, 256, 0, stream>>>(ZR, Opre, xe_bf, outs, outsb, n8);

    // ================= attention pooling -> proto (bf16 ws) ====================
    hipMemsetAsync(sA1, 0, 256 * sizeof(float), stream);
    colstats_bf<<<256, 256, 0, stream>>>(outsb, sA1, sA2);
    att_finalize_kernel<<<1, 128, 0, stream>>>(sA1, sA2, scl, shf, 128);
    hipMemsetAsync(proto, 0, 128 * sizeof(float), stream);
    proto_bf<<<256, 256, 0, stream>>>(outsb, scl, shf, proto);

    // ============ dis1 + dec1 — cov stats + merged edge GEMM (compact halves) ==
    hipMemsetAsync(covA, 0, 16384 * sizeof(float), stream);
    cov_kernel<<<98, 256, 0, stream>>>(outsb, covA);
    quadform_kernel<<<1024, 128, 0, stream>>>(covA, sA1, wdd, bdd, s1, s2);
    bn_finalize_pq<<<1, 512, 0, stream>>>(s1, s2, dis1_g, dis1_bt, dis1_b, scl, shf, 512, 0, 1.0f / NV);
    bn_finalize_pq<<<1, 512, 0, stream>>>(s1, s2, dec1_g, dec1_bt, dec1_b, scl, shf, 512, 512, 1.0f / NV);
    edge_gather_sum<<<(ME + 15) / 16, 256, 0, stream>>>(outsb, vidx, ge);
    { dim3 g(16, MEP / 128);
      mfma_gemm_ef2<<<g, 256, 0, stream>>>(ge, wdd, we, scl, shf, bufE0, bufE1); }
    csr_gather_dis<<<NV / 4, 256, 0, stream>>>(bufE0, rowptr, csr, wdis2, dis2_b, pre22);
    csr_gather_bf<<<NV / 4, 256, 0, stream>>>(bufE1, 512, 0, rowptr, csr,
        nullptr, 0, hdec, 512, 0, nullptr, 0, 512, 1);

    // ================= dis2 tail =================
    hipMemsetAsync(s1, 0, 2048 * sizeof(float), stream);
    colstats2_kernel<<<64, 256, 0, stream>>>(pre22, NV, s1, s2);
    bn_finalize_kernel<<<1, 512, 0, stream>>>(s1, s2, dis2_g, dis2_bt, scl, shf, 2, 1.0f / NV);
    edge_gather2_kernel<<<(ME + 255) / 256, 256, 0, stream>>>(pre22, vidx, we, scl, shf, bufEf);
    csr_gather2_kernel<<<(NV + 255) / 256, 256, 0, stream>>>(bufEf, rowptr, csr, xdis);

    // ================= dec2 (output-side conv) =================
    hipMemsetAsync(s1, 0, 2048 * sizeof(float), stream);
    gemm(hdec, 512, wdec2, dec2_b, Greg, 128, 0, nullptr, 0, 1 << 30, 128, s1, s2, 128);
    bn_finalize_kernel<<<1, 512, 0, stream>>>(s1, s2, dec2_g, dec2_bt, scl, shf, 128, 1.0f / NV);
    edge_gather_bf<<<(ME + 15) / 16, 256, 0, stream>>>(Greg, vidx, we, scl, shf, bufE0, 128);
    csr_gather_bf<<<NV / 16, 256, 0, stream>>>(bufE0, 128, 0, rowptr, csr,
        x_de, 128, nullptr, 0, 0, nullptr, 0, 128, 0);
}